// Round 11
// baseline (453.756 us; speedup 1.0000x reference)
//
#include <hip/hip_runtime.h>
#include <hip/hip_cooperative_groups.h>

namespace cg = cooperative_groups;

#define NN 50000
#define NE 600000
#define F_IN 57
#define HID 128
#define NEG 0.2f
#define NB_SCAN ((NN + 255) / 256)

#define GIN_NODES 64
#define NB_GIN ((NN + GIN_NODES - 1) / GIN_NODES)
#define XST 68
#define NB_PACK 16
#define NB_ZERO ((NN / 4 + 255) / 256)

#define CSR_BLOCKS 1024

#define DN_NODES 64            // nodes per MFMA dense block (4 waves x 16)
#define NB_DENSE ((NN + DN_NODES - 1) / DN_NODES)

typedef unsigned short bf16_t;
typedef __attribute__((ext_vector_type(8))) short bf16x8;
typedef __attribute__((ext_vector_type(4))) float f32x4;

__device__ __forceinline__ float leaky(float v) { return v >= 0.f ? v : NEG * v; }
__device__ __forceinline__ float bf2f(bf16_t u) { return __uint_as_float(((unsigned)u) << 16); }
__device__ __forceinline__ bf16_t f2bf(float f) {
    unsigned u = __float_as_uint(f);
    return (bf16_t)((u + 0x7FFFu + ((u >> 16) & 1u)) >> 16);   // RNE
}

// ---------------- Front kernel: gat_in GEMM | weight pack | deg zero (block-range split) ----
__global__ __launch_bounds__(256) void k_front(
    const float* __restrict__ x, const float* __restrict__ Wg,
    const float* __restrict__ a_s, const float* __restrict__ a_d,
    const float* __restrict__ Wl, const float* __restrict__ Wr,
    bf16_t* __restrict__ h, float* __restrict__ hs, float* __restrict__ hd,
    bf16_t* __restrict__ Bp, int* __restrict__ deg) {
    int tid = threadIdx.x;

    if (blockIdx.x >= NB_GIN + NB_PACK) {
        // ---- deg zero ----
        int idx4 = (blockIdx.x - NB_GIN - NB_PACK) * 256 + tid;
        if (idx4 * 4 < NN) *(int4*)(deg + idx4 * 4) = (int4){0, 0, 0, 0};
        return;
    }
    if (blockIdx.x >= NB_GIN) {
        // ---- weight pack: Bp[((nt*8+kb)*64+lane)*8+j] = B[kb*32+(lane>>4)*8+j][nt*16+(lane&15)]
        int idx = (blockIdx.x - NB_GIN) * 256 + tid;
        if (idx >= 8 * 8 * 64) return;
        int lane = idx & 63;
        int kb = (idx >> 6) & 7;
        int nt = idx >> 9;
        int col = nt * 16 + (lane & 15);
        int kbase = kb * 32 + (lane >> 4) * 8;
        bf16_t v[8];
#pragma unroll
        for (int j = 0; j < 8; ++j) {
            int k = kbase + j;
            float w = (k < HID) ? Wl[k * HID + col] : Wr[(k - HID) * HID + col];
            v[j] = f2bf(w);
        }
        ushort4* o = (ushort4*)(Bp + (size_t)idx * 8);
        ushort4 lo, hi;
        lo.x = v[0]; lo.y = v[1]; lo.z = v[2]; lo.w = v[3];
        hi.x = v[4]; hi.y = v[5]; hi.z = v[6]; hi.w = v[7];
        o[0] = lo; o[1] = hi;
        return;
    }

    // ---- gat_in: tiled h = x @ Wg (bf16 out); hs = h.a_src; hd = h.a_dst ----
    __shared__ float WgS[F_IN * HID];
    __shared__ float xsT[F_IN][XST];
    int node0 = blockIdx.x * GIN_NODES;
    {
        const float4* g = (const float4*)Wg;
        float4* s = (float4*)WgS;
        for (int i = tid; i < F_IN * HID / 4; i += 256) s[i] = g[i];
    }
    for (int i = tid; i < GIN_NODES * F_IN; i += 256) {
        int n = i / F_IN;
        int k = i - n * F_IN;
        int gn = node0 + n;
        if (gn >= NN) gn = NN - 1;
        xsT[k][n] = x[gn * F_IN + k];
    }
    __syncthreads();

    int fq = tid & 31, nq = tid >> 5;
    int f0 = fq * 4, nb = nq * 8;
    float acc[8][4];
#pragma unroll
    for (int i = 0; i < 8; ++i)
#pragma unroll
        for (int j = 0; j < 4; ++j) acc[i][j] = 0.f;

    for (int k = 0; k < F_IN; ++k) {
        float4 w = *(const float4*)&WgS[k * HID + f0];
        float4 xa = *(const float4*)&xsT[k][nb];
        float4 xb = *(const float4*)&xsT[k][nb + 4];
        float xv[8] = {xa.x, xa.y, xa.z, xa.w, xb.x, xb.y, xb.z, xb.w};
        float wv[4] = {w.x, w.y, w.z, w.w};
#pragma unroll
        for (int i = 0; i < 8; ++i)
#pragma unroll
            for (int j = 0; j < 4; ++j)
                acc[i][j] = fmaf(xv[i], wv[j], acc[i][j]);
    }

    float4 as4 = *(const float4*)(a_s + f0);
    float4 ad4 = *(const float4*)(a_d + f0);
    float ps[8], pd[8];
#pragma unroll
    for (int i = 0; i < 8; ++i) {
        int gn = node0 + nb + i;
        if (gn < NN) {
            ushort4 hv;
            hv.x = f2bf(acc[i][0]); hv.y = f2bf(acc[i][1]);
            hv.z = f2bf(acc[i][2]); hv.w = f2bf(acc[i][3]);
            *(ushort4*)(h + (size_t)gn * HID + f0) = hv;
        }
        ps[i] = acc[i][0] * as4.x + acc[i][1] * as4.y + acc[i][2] * as4.z + acc[i][3] * as4.w;
        pd[i] = acc[i][0] * ad4.x + acc[i][1] * ad4.y + acc[i][2] * ad4.z + acc[i][3] * ad4.w;
    }
#pragma unroll
    for (int off = 16; off > 0; off >>= 1) {
#pragma unroll
        for (int i = 0; i < 8; ++i) {
            ps[i] += __shfl_xor(ps[i], off);
            pd[i] += __shfl_xor(pd[i], off);
        }
    }
    if (fq == 0) {
#pragma unroll
        for (int i = 0; i < 8; ++i) {
            int gn = node0 + nb + i;
            if (gn < NN) { hs[gn] = ps[i]; hd[gn] = pd[i]; }
        }
    }
}

// ---------------- Cooperative CSR build: hist -> scan -> prefix -> fill ----------------
__global__ __launch_bounds__(256) void k_csr(
    const int* __restrict__ src, const int* __restrict__ dst,
    int* __restrict__ deg, int* __restrict__ rptr, int* __restrict__ wptr,
    int* __restrict__ bsum, int* __restrict__ esrc) {
    cg::grid_group grid = cg::this_grid();
    int tid = threadIdx.x;
    int gid = blockIdx.x * 256 + tid;
    int gsz = gridDim.x * 256;
    __shared__ int s[256];
    __shared__ int wsum[4];

    // phase 0: degree histogram
    for (int e = gid; e < NE; e += gsz) atomicAdd(&deg[dst[e]], 1);
    grid.sync();

    // phase 1: per-256-tile exclusive scan, tile totals to bsum
    for (int tile = blockIdx.x; tile < NB_SCAN; tile += gridDim.x) {
        int i = tile * 256 + tid;
        int v = (i < NN) ? deg[i] : 0;
        s[tid] = v;
        __syncthreads();
        for (int off = 1; off < 256; off <<= 1) {
            int xv = (tid >= off) ? s[tid - off] : 0;
            __syncthreads();
            s[tid] += xv;
            __syncthreads();
        }
        if (i < NN) rptr[i] = s[tid] - v;
        if (tid == 255) bsum[tile] = s[255];
        __syncthreads();
    }
    grid.sync();

    // phase 2: add tile prefix; emit wptr copy
    for (int tile = blockIdx.x; tile < NB_SCAN; tile += gridDim.x) {
        int v = (tid < NB_SCAN && tid < tile) ? bsum[tid] : 0;
#pragma unroll
        for (int off = 32; off > 0; off >>= 1) v += __shfl_xor(v, off);
        if ((tid & 63) == 0) wsum[tid >> 6] = v;
        __syncthreads();
        int pre = wsum[0] + wsum[1] + wsum[2] + wsum[3];
        int i = tile * 256 + tid;
        if (i < NN) {
            int r = rptr[i] + pre;
            rptr[i] = r;
            wptr[i] = r;
        }
        __syncthreads();
    }
    grid.sync();

    // phase 3: fill edge lists
    for (int e = gid; e < NE; e += gsz) {
        int d = dst[e];
        int pos = atomicAdd(&wptr[d], 1);
        esrc[pos] = src[e];
    }
}

// ---------------- GAT aggregation: wave-per-node, barrier-free ----------------
__global__ __launch_bounds__(256) void k_gat_agg(
    const int* __restrict__ rptr, const int* __restrict__ deg,
    const int* __restrict__ esrc, const float* __restrict__ hs,
    const float* __restrict__ hd, const bf16_t* __restrict__ h,
    const float* __restrict__ bg, bf16_t* __restrict__ h1) {
    int tid = threadIdx.x;
    int row = blockIdx.x * 4 + (tid >> 6);
    if (row >= NN) return;
    int lane = tid & 63;
    int slot = lane >> 4;
    int f8 = lane & 15;

    int start = rptr[row];
    int dn = deg[row];
    int end = start + dn;
    float hdr = hd[row];
    float wself = __expf(leaky(hs[row] + hdr));

    float a[8];
#pragma unroll
    for (int j = 0; j < 8; ++j) a[j] = 0.f;
    float denL = 0.f;

    if (slot == 0) {
        bf16x8 r = *(const bf16x8*)(h + (size_t)row * HID + f8 * 8);
#pragma unroll
        for (int j = 0; j < 8; ++j) a[j] = wself * bf2f((bf16_t)r[j]);
    }

    int e = start;
    for (; e + 8 <= end; e += 8) {
        int s0 = esrc[e + slot];
        int s1 = esrc[e + 4 + slot];
        float w0 = __expf(leaky(hs[s0] + hdr));
        float w1 = __expf(leaky(hs[s1] + hdr));
        bf16x8 r0 = *(const bf16x8*)(h + (size_t)s0 * HID + f8 * 8);
        bf16x8 r1 = *(const bf16x8*)(h + (size_t)s1 * HID + f8 * 8);
        denL += w0 + w1;
#pragma unroll
        for (int j = 0; j < 8; ++j) {
            a[j] = fmaf(w0, bf2f((bf16_t)r0[j]), a[j]);
            a[j] = fmaf(w1, bf2f((bf16_t)r1[j]), a[j]);
        }
    }
    for (; e < end; e += 4) {
        int i = e + slot;
        bool act = i < end;
        int sn = esrc[act ? i : end - 1];
        float w = act ? __expf(leaky(hs[sn] + hdr)) : 0.f;
        bf16x8 r = *(const bf16x8*)(h + (size_t)sn * HID + f8 * 8);
        denL += w;
#pragma unroll
        for (int j = 0; j < 8; ++j) a[j] = fmaf(w, bf2f((bf16_t)r[j]), a[j]);
    }

#pragma unroll
    for (int j = 0; j < 8; ++j) {
        a[j] += __shfl_xor(a[j], 16);
        a[j] += __shfl_xor(a[j], 32);
    }
    denL += __shfl_xor(denL, 16);
    denL += __shfl_xor(denL, 32);
    float inv = 1.f / (wself + denL);

    if (lane < 16) {
        float4 b0 = *(const float4*)(bg + lane * 8);
        float4 b1 = *(const float4*)(bg + lane * 8 + 4);
        float bb[8] = {b0.x, b0.y, b0.z, b0.w, b1.x, b1.y, b1.z, b1.w};
        bf16x8 o;
#pragma unroll
        for (int j = 0; j < 8; ++j) {
            float v = a[j] * inv + bb[j];
            o[j] = (short)f2bf(v > 0.f ? v : 0.f);
        }
        *(bf16x8*)(h1 + (size_t)row * HID + lane * 8) = o;
    }
}

// ---------------- SAGE mean gather: wave-per-node, barrier-free ----------------
__global__ __launch_bounds__(256) void k_sage_gather(
    const int* __restrict__ rptr, const int* __restrict__ deg,
    const int* __restrict__ esrc, const bf16_t* __restrict__ h1,
    bf16_t* __restrict__ mean) {
    int tid = threadIdx.x;
    int row = blockIdx.x * 4 + (tid >> 6);
    if (row >= NN) return;
    int lane = tid & 63;
    int slot = lane >> 4;
    int f8 = lane & 15;

    int start = rptr[row];
    int dn = deg[row];
    int end = start + dn;

    float a[8];
#pragma unroll
    for (int j = 0; j < 8; ++j) a[j] = 0.f;

    int e = start;
    for (; e + 8 <= end; e += 8) {
        int s0 = esrc[e + slot];
        int s1 = esrc[e + 4 + slot];
        bf16x8 r0 = *(const bf16x8*)(h1 + (size_t)s0 * HID + f8 * 8);
        bf16x8 r1 = *(const bf16x8*)(h1 + (size_t)s1 * HID + f8 * 8);
#pragma unroll
        for (int j = 0; j < 8; ++j)
            a[j] += bf2f((bf16_t)r0[j]) + bf2f((bf16_t)r1[j]);
    }
    for (; e < end; e += 4) {
        int i = e + slot;
        bool act = i < end;
        int sn = esrc[act ? i : end - 1];
        bf16x8 r = *(const bf16x8*)(h1 + (size_t)sn * HID + f8 * 8);
        float w = act ? 1.f : 0.f;
#pragma unroll
        for (int j = 0; j < 8; ++j) a[j] = fmaf(w, bf2f((bf16_t)r[j]), a[j]);
    }

#pragma unroll
    for (int j = 0; j < 8; ++j) {
        a[j] += __shfl_xor(a[j], 16);
        a[j] += __shfl_xor(a[j], 32);
    }
    if (lane < 16) {
        float inv = 1.f / (float)(dn > 0 ? dn : 1);
        bf16x8 o;
#pragma unroll
        for (int j = 0; j < 8; ++j) o[j] = (short)f2bf(a[j] * inv);
        *(bf16x8*)(mean + (size_t)row * HID + lane * 8) = o;
    }
}

// ---------------- Dense via MFMA: out = sigmoid(relu([mean|h1] @ [Wl;Wr] + bl) @ Wout + bout) ----
__global__ __launch_bounds__(256) void k_dense_mfma(
    const bf16_t* __restrict__ mean, const bf16_t* __restrict__ h1,
    const bf16_t* __restrict__ Bp, const float* __restrict__ bl,
    const float* __restrict__ Wout, const float* __restrict__ bout,
    float* __restrict__ out) {
    int tid = threadIdx.x;
    int lane = tid & 63;
    int wv = tid >> 6;
    int node0 = blockIdx.x * DN_NODES + wv * 16;
    int arow = lane & 15;
    int kg = lane >> 4;
    int gn = node0 + arow;
    if (gn >= NN) gn = NN - 1;
    const bf16_t* mrow = mean + (size_t)gn * HID;
    const bf16_t* srow = h1 + (size_t)gn * HID;
    const bf16x8* bp = (const bf16x8*)Bp;

    f32x4 acc[8];
#pragma unroll
    for (int n = 0; n < 8; ++n) acc[n] = (f32x4){0.f, 0.f, 0.f, 0.f};

#pragma unroll
    for (int kb = 0; kb < 8; ++kb) {
        int k0 = kb * 32 + kg * 8;
        bf16x8 a = (kb < 4) ? *(const bf16x8*)(mrow + k0)
                            : *(const bf16x8*)(srow + (k0 - HID));
#pragma unroll
        for (int n = 0; n < 8; ++n) {
            bf16x8 b = bp[((n * 8 + kb) << 6) + lane];
            acc[n] = __builtin_amdgcn_mfma_f32_16x16x32_bf16(a, b, acc[n], 0, 0, 0);
        }
    }

    float pr[4] = {0.f, 0.f, 0.f, 0.f};
#pragma unroll
    for (int n = 0; n < 8; ++n) {
        int f = n * 16 + arow;
        float b = bl[f];
        float wo = Wout[f];
#pragma unroll
        for (int r = 0; r < 4; ++r) {
            float v = fmaxf(acc[n][r] + b, 0.f);
            pr[r] = fmaf(v, wo, pr[r]);
        }
    }
#pragma unroll
    for (int off = 8; off > 0; off >>= 1) {
#pragma unroll
        for (int r = 0; r < 4; ++r) pr[r] += __shfl_xor(pr[r], off);
    }
    if (arow == 0) {
        float bo = bout[0];
#pragma unroll
        for (int r = 0; r < 4; ++r) {
            int gno = node0 + kg * 4 + r;
            if (gno < NN) out[gno] = 1.f / (1.f + __expf(-(pr[r] + bo)));
        }
    }
}

extern "C" void kernel_launch(void* const* d_in, const int* in_sizes, int n_in,
                              void* d_out, int out_size, void* d_ws, size_t ws_size,
                              hipStream_t stream) {
    const float* x    = (const float*)d_in[0];
    const int*   ei   = (const int*)d_in[1];
    const float* Wg   = (const float*)d_in[2];
    const float* a_s  = (const float*)d_in[3];
    const float* a_d  = (const float*)d_in[4];
    const float* bg   = (const float*)d_in[5];
    const float* Wl   = (const float*)d_in[6];
    const float* bl   = (const float*)d_in[7];
    const float* Wr   = (const float*)d_in[8];
    const float* Wout = (const float*)d_in[9];
    const float* bout = (const float*)d_in[10];
    float* out = (float*)d_out;

    const int* src = ei;
    const int* dst = ei + NE;

    bf16_t* h    = (bf16_t*)d_ws;                  // NN*HID bf16
    bf16_t* h1   = h + (size_t)NN * HID;           // NN*HID bf16
    bf16_t* mean = h1 + (size_t)NN * HID;          // NN*HID bf16
    bf16_t* Bp   = mean + (size_t)NN * HID;        // 64 KB packed weights
    float* hs = (float*)(Bp + 8 * 8 * 64 * 8);     // NN
    float* hd = hs + NN;                           // NN
    int* deg  = (int*)(hd + NN);                   // NN (zeroed in k_front)
    int* wptr = deg + NN;                          // NN (written by k_csr)
    int* rptr = wptr + NN;                         // NN
    int* bsum = rptr + NN;                         // NB_SCAN
    int* esrc = bsum + NB_SCAN;                    // NE

    k_front<<<NB_GIN + NB_PACK + NB_ZERO, 256, 0, stream>>>(
        x, Wg, a_s, a_d, Wl, Wr, h, hs, hd, Bp, deg);

    {
        void* args[] = {(void*)&src, (void*)&dst, (void*)&deg, (void*)&rptr,
                        (void*)&wptr, (void*)&bsum, (void*)&esrc};
        hipLaunchCooperativeKernel((void*)k_csr, dim3(CSR_BLOCKS), dim3(256),
                                   args, 0, stream);
    }

    k_gat_agg<<<(NN + 3) / 4, 256, 0, stream>>>(rptr, deg, esrc, hs, hd, h, bg, h1);
    k_sage_gather<<<(NN + 3) / 4, 256, 0, stream>>>(rptr, deg, esrc, h1, mean);
    k_dense_mfma<<<NB_DENSE, 256, 0, stream>>>(mean, h1, Bp, bl, Wout, bout, out);
}

// Round 12
// 174.970 us; speedup vs baseline: 2.5933x; 2.5933x over previous
//
#include <hip/hip_runtime.h>

#define NN 50000
#define NE 600000
#define F_IN 57
#define HID 128
#define NEG 0.2f
#define NB_SCAN ((NN + 255) / 256)

#define GIN_NODES 64
#define NB_GIN ((NN + GIN_NODES - 1) / GIN_NODES)
#define XST 68
#define NB_PACK 16
#define NZERO_INT4 ((2 * NN + 4 + 3) / 4)
#define NB_ZERO ((NZERO_INT4 + 255) / 256)

#define DN_NODES 64            // nodes per MFMA dense block (4 waves x 16)
#define NB_DENSE ((NN + DN_NODES - 1) / DN_NODES)

typedef unsigned short bf16_t;
typedef __attribute__((ext_vector_type(8))) short bf16x8;
typedef __attribute__((ext_vector_type(4))) float f32x4;

__device__ __forceinline__ float leaky(float v) { return v >= 0.f ? v : NEG * v; }
__device__ __forceinline__ float bf2f(bf16_t u) { return __uint_as_float(((unsigned)u) << 16); }
__device__ __forceinline__ bf16_t f2bf(float f) {
    unsigned u = __float_as_uint(f);
    return (bf16_t)((u + 0x7FFFu + ((u >> 16) & 1u)) >> 16);   // RNE
}

// ---------------- Front: gat_in GEMM | weight pack | zero(deg,fillcnt,done) ----------------
__global__ __launch_bounds__(256) void k_front(
    const float* __restrict__ x, const float* __restrict__ Wg,
    const float* __restrict__ a_s, const float* __restrict__ a_d,
    const float* __restrict__ Wl, const float* __restrict__ Wr,
    bf16_t* __restrict__ h, float* __restrict__ hs, float* __restrict__ hd,
    bf16_t* __restrict__ Bp, int* __restrict__ zbase) {
    int tid = threadIdx.x;

    if (blockIdx.x >= NB_GIN + NB_PACK) {
        // ---- zero deg/fillcnt/done ----
        int idx4 = (blockIdx.x - NB_GIN - NB_PACK) * 256 + tid;
        if (idx4 < NZERO_INT4) *(int4*)(zbase + idx4 * 4) = (int4){0, 0, 0, 0};
        return;
    }
    if (blockIdx.x >= NB_GIN) {
        // ---- weight pack: Bp[((nt*8+kb)*64+lane)*8+j] = B[kb*32+(lane>>4)*8+j][nt*16+(lane&15)]
        int idx = (blockIdx.x - NB_GIN) * 256 + tid;
        if (idx >= 8 * 8 * 64) return;
        int lane = idx & 63;
        int kb = (idx >> 6) & 7;
        int nt = idx >> 9;
        int col = nt * 16 + (lane & 15);
        int kbase = kb * 32 + (lane >> 4) * 8;
        bf16_t v[8];
#pragma unroll
        for (int j = 0; j < 8; ++j) {
            int k = kbase + j;
            float w = (k < HID) ? Wl[k * HID + col] : Wr[(k - HID) * HID + col];
            v[j] = f2bf(w);
        }
        ushort4* o = (ushort4*)(Bp + (size_t)idx * 8);
        ushort4 lo, hi;
        lo.x = v[0]; lo.y = v[1]; lo.z = v[2]; lo.w = v[3];
        hi.x = v[4]; hi.y = v[5]; hi.z = v[6]; hi.w = v[7];
        o[0] = lo; o[1] = hi;
        return;
    }

    // ---- gat_in: tiled h = x @ Wg (bf16 out); hs = h.a_src; hd = h.a_dst ----
    __shared__ float WgS[F_IN * HID];
    __shared__ float xsT[F_IN][XST];
    int node0 = blockIdx.x * GIN_NODES;
    {
        const float4* g = (const float4*)Wg;
        float4* s = (float4*)WgS;
        for (int i = tid; i < F_IN * HID / 4; i += 256) s[i] = g[i];
    }
    for (int i = tid; i < GIN_NODES * F_IN; i += 256) {
        int n = i / F_IN;
        int k = i - n * F_IN;
        int gn = node0 + n;
        if (gn >= NN) gn = NN - 1;
        xsT[k][n] = x[gn * F_IN + k];
    }
    __syncthreads();

    int fq = tid & 31, nq = tid >> 5;
    int f0 = fq * 4, nb = nq * 8;
    float acc[8][4];
#pragma unroll
    for (int i = 0; i < 8; ++i)
#pragma unroll
        for (int j = 0; j < 4; ++j) acc[i][j] = 0.f;

    for (int k = 0; k < F_IN; ++k) {
        float4 w = *(const float4*)&WgS[k * HID + f0];
        float4 xa = *(const float4*)&xsT[k][nb];
        float4 xb = *(const float4*)&xsT[k][nb + 4];
        float xv[8] = {xa.x, xa.y, xa.z, xa.w, xb.x, xb.y, xb.z, xb.w};
        float wv[4] = {w.x, w.y, w.z, w.w};
#pragma unroll
        for (int i = 0; i < 8; ++i)
#pragma unroll
            for (int j = 0; j < 4; ++j)
                acc[i][j] = fmaf(xv[i], wv[j], acc[i][j]);
    }

    float4 as4 = *(const float4*)(a_s + f0);
    float4 ad4 = *(const float4*)(a_d + f0);
    float ps[8], pd[8];
#pragma unroll
    for (int i = 0; i < 8; ++i) {
        int gn = node0 + nb + i;
        if (gn < NN) {
            ushort4 hv;
            hv.x = f2bf(acc[i][0]); hv.y = f2bf(acc[i][1]);
            hv.z = f2bf(acc[i][2]); hv.w = f2bf(acc[i][3]);
            *(ushort4*)(h + (size_t)gn * HID + f0) = hv;
        }
        ps[i] = acc[i][0] * as4.x + acc[i][1] * as4.y + acc[i][2] * as4.z + acc[i][3] * as4.w;
        pd[i] = acc[i][0] * ad4.x + acc[i][1] * ad4.y + acc[i][2] * ad4.z + acc[i][3] * ad4.w;
    }
#pragma unroll
    for (int off = 16; off > 0; off >>= 1) {
#pragma unroll
        for (int i = 0; i < 8; ++i) {
            ps[i] += __shfl_xor(ps[i], off);
            pd[i] += __shfl_xor(pd[i], off);
        }
    }
    if (fq == 0) {
#pragma unroll
        for (int i = 0; i < 8; ++i) {
            int gn = node0 + nb + i;
            if (gn < NN) { hs[gn] = ps[i]; hd[gn] = pd[i]; }
        }
    }
}

// ---------------- CSR: histogram ----------------
__global__ void k_hist(const int* __restrict__ dst, int* __restrict__ deg) {
    int e = blockIdx.x * blockDim.x + threadIdx.x;
    if (e < NE) atomicAdd(&deg[dst[e]], 1);
}

// ---------------- CSR: per-tile scan + last-block tile-prefix (no grid sync) ----------------
__global__ void k_scan(const int* __restrict__ deg, int* __restrict__ rptr,
                       int* __restrict__ bsum, int* __restrict__ bpre,
                       int* __restrict__ done) {
    int t = threadIdx.x;
    int tile = blockIdx.x;
    int i = tile * 256 + t;
    int v = (i < NN) ? deg[i] : 0;
    __shared__ int s[256];
    __shared__ int islast;
    s[t] = v;
    __syncthreads();
    for (int off = 1; off < 256; off <<= 1) {
        int xv = (t >= off) ? s[t - off] : 0;
        __syncthreads();
        s[t] += xv;
        __syncthreads();
    }
    if (i < NN) rptr[i] = s[t] - v;          // exclusive within tile
    if (t == 255) bsum[tile] = s[255];
    __threadfence();                          // publish bsum device-wide
    if (t == 0) islast = (atomicAdd(done, 1) == NB_SCAN - 1);
    __syncthreads();
    if (!islast) return;
    // last block: exclusive scan of the 196 tile totals (coherent atomic fetches)
    int b = (t < NB_SCAN) ? atomicAdd(&bsum[t], 0) : 0;
    __syncthreads();
    s[t] = b;
    __syncthreads();
    for (int off = 1; off < 256; off <<= 1) {
        int xv = (t >= off) ? s[t - off] : 0;
        __syncthreads();
        s[t] += xv;
        __syncthreads();
    }
    if (t < NB_SCAN) bpre[t] = s[t] - b;
}

// ---------------- CSR: fill (pos = bpre[tile] + rptr[d] + fillcnt[d]++) ----------------
__global__ void k_fill(const int* __restrict__ src, const int* __restrict__ dst,
                       const int* __restrict__ rptr, const int* __restrict__ bpre,
                       int* __restrict__ fillcnt, int* __restrict__ esrc) {
    int e = blockIdx.x * blockDim.x + threadIdx.x;
    if (e >= NE) return;
    int d = dst[e];
    int pos = rptr[d] + bpre[d >> 8] + atomicAdd(&fillcnt[d], 1);
    esrc[pos] = src[e];
}

// ---------------- GAT aggregation: wave-per-node, barrier-free ----------------
__global__ __launch_bounds__(256) void k_gat_agg(
    const int* __restrict__ rptr, const int* __restrict__ bpre,
    const int* __restrict__ deg, const int* __restrict__ esrc,
    const float* __restrict__ hs, const float* __restrict__ hd,
    const bf16_t* __restrict__ h, const float* __restrict__ bg,
    bf16_t* __restrict__ h1) {
    int tid = threadIdx.x;
    int row = blockIdx.x * 4 + (tid >> 6);
    if (row >= NN) return;
    int lane = tid & 63;
    int slot = lane >> 4;
    int f8 = lane & 15;

    int start = rptr[row] + bpre[row >> 8];
    int dn = deg[row];
    int end = start + dn;
    float hdr = hd[row];
    float wself = __expf(leaky(hs[row] + hdr));

    float a[8];
#pragma unroll
    for (int j = 0; j < 8; ++j) a[j] = 0.f;
    float denL = 0.f;

    if (slot == 0) {
        bf16x8 r = *(const bf16x8*)(h + (size_t)row * HID + f8 * 8);
#pragma unroll
        for (int j = 0; j < 8; ++j) a[j] = wself * bf2f((bf16_t)r[j]);
    }

    int e = start;
    for (; e + 8 <= end; e += 8) {
        int s0 = esrc[e + slot];
        int s1 = esrc[e + 4 + slot];
        float w0 = __expf(leaky(hs[s0] + hdr));
        float w1 = __expf(leaky(hs[s1] + hdr));
        bf16x8 r0 = *(const bf16x8*)(h + (size_t)s0 * HID + f8 * 8);
        bf16x8 r1 = *(const bf16x8*)(h + (size_t)s1 * HID + f8 * 8);
        denL += w0 + w1;
#pragma unroll
        for (int j = 0; j < 8; ++j) {
            a[j] = fmaf(w0, bf2f((bf16_t)r0[j]), a[j]);
            a[j] = fmaf(w1, bf2f((bf16_t)r1[j]), a[j]);
        }
    }
    for (; e < end; e += 4) {
        int i = e + slot;
        bool act = i < end;
        int sn = esrc[act ? i : end - 1];
        float w = act ? __expf(leaky(hs[sn] + hdr)) : 0.f;
        bf16x8 r = *(const bf16x8*)(h + (size_t)sn * HID + f8 * 8);
        denL += w;
#pragma unroll
        for (int j = 0; j < 8; ++j) a[j] = fmaf(w, bf2f((bf16_t)r[j]), a[j]);
    }

#pragma unroll
    for (int j = 0; j < 8; ++j) {
        a[j] += __shfl_xor(a[j], 16);
        a[j] += __shfl_xor(a[j], 32);
    }
    denL += __shfl_xor(denL, 16);
    denL += __shfl_xor(denL, 32);
    float inv = 1.f / (wself + denL);

    if (lane < 16) {
        float4 b0 = *(const float4*)(bg + lane * 8);
        float4 b1 = *(const float4*)(bg + lane * 8 + 4);
        float bb[8] = {b0.x, b0.y, b0.z, b0.w, b1.x, b1.y, b1.z, b1.w};
        bf16x8 o;
#pragma unroll
        for (int j = 0; j < 8; ++j) {
            float v = a[j] * inv + bb[j];
            o[j] = (short)f2bf(v > 0.f ? v : 0.f);
        }
        *(bf16x8*)(h1 + (size_t)row * HID + lane * 8) = o;
    }
}

// ---------------- SAGE mean gather: wave-per-node, barrier-free ----------------
__global__ __launch_bounds__(256) void k_sage_gather(
    const int* __restrict__ rptr, const int* __restrict__ bpre,
    const int* __restrict__ deg, const int* __restrict__ esrc,
    const bf16_t* __restrict__ h1, bf16_t* __restrict__ mean) {
    int tid = threadIdx.x;
    int row = blockIdx.x * 4 + (tid >> 6);
    if (row >= NN) return;
    int lane = tid & 63;
    int slot = lane >> 4;
    int f8 = lane & 15;

    int start = rptr[row] + bpre[row >> 8];
    int dn = deg[row];
    int end = start + dn;

    float a[8];
#pragma unroll
    for (int j = 0; j < 8; ++j) a[j] = 0.f;

    int e = start;
    for (; e + 8 <= end; e += 8) {
        int s0 = esrc[e + slot];
        int s1 = esrc[e + 4 + slot];
        bf16x8 r0 = *(const bf16x8*)(h1 + (size_t)s0 * HID + f8 * 8);
        bf16x8 r1 = *(const bf16x8*)(h1 + (size_t)s1 * HID + f8 * 8);
#pragma unroll
        for (int j = 0; j < 8; ++j)
            a[j] += bf2f((bf16_t)r0[j]) + bf2f((bf16_t)r1[j]);
    }
    for (; e < end; e += 4) {
        int i = e + slot;
        bool act = i < end;
        int sn = esrc[act ? i : end - 1];
        bf16x8 r = *(const bf16x8*)(h1 + (size_t)sn * HID + f8 * 8);
        float w = act ? 1.f : 0.f;
#pragma unroll
        for (int j = 0; j < 8; ++j) a[j] = fmaf(w, bf2f((bf16_t)r[j]), a[j]);
    }

#pragma unroll
    for (int j = 0; j < 8; ++j) {
        a[j] += __shfl_xor(a[j], 16);
        a[j] += __shfl_xor(a[j], 32);
    }
    if (lane < 16) {
        float inv = 1.f / (float)(dn > 0 ? dn : 1);
        bf16x8 o;
#pragma unroll
        for (int j = 0; j < 8; ++j) o[j] = (short)f2bf(a[j] * inv);
        *(bf16x8*)(mean + (size_t)row * HID + lane * 8) = o;
    }
}

// ---------------- Dense via MFMA: out = sigmoid(relu([mean|h1] @ [Wl;Wr] + bl) @ Wout + bout) ----
__global__ __launch_bounds__(256) void k_dense_mfma(
    const bf16_t* __restrict__ mean, const bf16_t* __restrict__ h1,
    const bf16_t* __restrict__ Bp, const float* __restrict__ bl,
    const float* __restrict__ Wout, const float* __restrict__ bout,
    float* __restrict__ out) {
    int tid = threadIdx.x;
    int lane = tid & 63;
    int wv = tid >> 6;
    int node0 = blockIdx.x * DN_NODES + wv * 16;
    int arow = lane & 15;
    int kg = lane >> 4;
    int gn = node0 + arow;
    if (gn >= NN) gn = NN - 1;
    const bf16_t* mrow = mean + (size_t)gn * HID;
    const bf16_t* srow = h1 + (size_t)gn * HID;
    const bf16x8* bp = (const bf16x8*)Bp;

    f32x4 acc[8];
#pragma unroll
    for (int n = 0; n < 8; ++n) acc[n] = (f32x4){0.f, 0.f, 0.f, 0.f};

#pragma unroll
    for (int kb = 0; kb < 8; ++kb) {
        int k0 = kb * 32 + kg * 8;
        bf16x8 a = (kb < 4) ? *(const bf16x8*)(mrow + k0)
                            : *(const bf16x8*)(srow + (k0 - HID));
#pragma unroll
        for (int n = 0; n < 8; ++n) {
            bf16x8 b = bp[((n * 8 + kb) << 6) + lane];
            acc[n] = __builtin_amdgcn_mfma_f32_16x16x32_bf16(a, b, acc[n], 0, 0, 0);
        }
    }

    float pr[4] = {0.f, 0.f, 0.f, 0.f};
#pragma unroll
    for (int n = 0; n < 8; ++n) {
        int f = n * 16 + arow;
        float b = bl[f];
        float wo = Wout[f];
#pragma unroll
        for (int r = 0; r < 4; ++r) {
            float v = fmaxf(acc[n][r] + b, 0.f);
            pr[r] = fmaf(v, wo, pr[r]);
        }
    }
#pragma unroll
    for (int off = 8; off > 0; off >>= 1) {
#pragma unroll
        for (int r = 0; r < 4; ++r) pr[r] += __shfl_xor(pr[r], off);
    }
    if (arow == 0) {
        float bo = bout[0];
#pragma unroll
        for (int r = 0; r < 4; ++r) {
            int gno = node0 + kg * 4 + r;
            if (gno < NN) out[gno] = 1.f / (1.f + __expf(-(pr[r] + bo)));
        }
    }
}

extern "C" void kernel_launch(void* const* d_in, const int* in_sizes, int n_in,
                              void* d_out, int out_size, void* d_ws, size_t ws_size,
                              hipStream_t stream) {
    const float* x    = (const float*)d_in[0];
    const int*   ei   = (const int*)d_in[1];
    const float* Wg   = (const float*)d_in[2];
    const float* a_s  = (const float*)d_in[3];
    const float* a_d  = (const float*)d_in[4];
    const float* bg   = (const float*)d_in[5];
    const float* Wl   = (const float*)d_in[6];
    const float* bl   = (const float*)d_in[7];
    const float* Wr   = (const float*)d_in[8];
    const float* Wout = (const float*)d_in[9];
    const float* bout = (const float*)d_in[10];
    float* out = (float*)d_out;

    const int* src = ei;
    const int* dst = ei + NE;

    bf16_t* h    = (bf16_t*)d_ws;                  // NN*HID bf16
    bf16_t* h1   = h + (size_t)NN * HID;           // NN*HID bf16
    bf16_t* mean = h1 + (size_t)NN * HID;          // NN*HID bf16
    bf16_t* Bp   = mean + (size_t)NN * HID;        // 64 KB packed weights
    float* hs = (float*)(Bp + 8 * 8 * 64 * 8);     // NN
    float* hd = hs + NN;                           // NN
    int* deg     = (int*)(hd + NN);                // NN   -- zero region start
    int* fillcnt = deg + NN;                       // NN
    int* done    = fillcnt + NN;                   // 4    -- zero region end
    int* rptr    = done + 4;                       // NN
    int* bsum    = rptr + NN;                      // 256
    int* bpre    = bsum + 256;                     // 256
    int* esrc    = bpre + 256;                     // NE

    k_front<<<NB_GIN + NB_PACK + NB_ZERO, 256, 0, stream>>>(
        x, Wg, a_s, a_d, Wl, Wr, h, hs, hd, Bp, deg);

    k_hist<<<(NE + 255) / 256, 256, 0, stream>>>(dst, deg);
    k_scan<<<NB_SCAN, 256, 0, stream>>>(deg, rptr, bsum, bpre, done);
    k_fill<<<(NE + 255) / 256, 256, 0, stream>>>(src, dst, rptr, bpre, fillcnt, esrc);

    k_gat_agg<<<(NN + 3) / 4, 256, 0, stream>>>(rptr, bpre, deg, esrc, hs, hd, h, bg, h1);
    k_sage_gather<<<(NN + 3) / 4, 256, 0, stream>>>(rptr, bpre, deg, esrc, h1, mean);
    k_dense_mfma<<<NB_DENSE, 256, 0, stream>>>(mean, h1, Bp, bl, Wout, bout, out);
}

// Round 13
// 170.176 us; speedup vs baseline: 2.6664x; 1.0282x over previous
//
#include <hip/hip_runtime.h>

#define NN 50000
#define NE 600000
#define F_IN 57
#define HID 128
#define NEG 0.2f
#define NB_SCAN ((NN + 255) / 256)

#define GIN_NODES 64
#define NB_GIN ((NN + GIN_NODES - 1) / GIN_NODES)
#define XST 68
#define NB_PACK 16
#define NZERO_INT4 ((2 * NN + 4 + 3) / 4)
#define NB_ZERO ((NZERO_INT4 + 255) / 256)

#define SD_NODES 16
#define NB_SD (NN / SD_NODES)   // 3125 exactly, no tail

typedef unsigned short bf16_t;
typedef __attribute__((ext_vector_type(8))) short bf16x8;
typedef __attribute__((ext_vector_type(4))) float f32x4;

__device__ __forceinline__ float leaky(float v) { return v >= 0.f ? v : NEG * v; }
__device__ __forceinline__ float bf2f(bf16_t u) { return __uint_as_float(((unsigned)u) << 16); }
__device__ __forceinline__ bf16_t f2bf(float f) {
    unsigned u = __float_as_uint(f);
    return (bf16_t)((u + 0x7FFFu + ((u >> 16) & 1u)) >> 16);   // RNE
}

// ---------------- Front: gat_in GEMM | weight pack | zero(deg,fillcnt,done) ----------------
__global__ __launch_bounds__(256) void k_front(
    const float* __restrict__ x, const float* __restrict__ Wg,
    const float* __restrict__ a_s, const float* __restrict__ a_d,
    const float* __restrict__ Wl, const float* __restrict__ Wr,
    bf16_t* __restrict__ h, float* __restrict__ hs, float* __restrict__ hd,
    bf16_t* __restrict__ Bp, int* __restrict__ zbase) {
    int tid = threadIdx.x;

    if (blockIdx.x >= NB_GIN + NB_PACK) {
        int idx4 = (blockIdx.x - NB_GIN - NB_PACK) * 256 + tid;
        if (idx4 < NZERO_INT4) *(int4*)(zbase + idx4 * 4) = (int4){0, 0, 0, 0};
        return;
    }
    if (blockIdx.x >= NB_GIN) {
        // Bp[((nt*8+kb)*64+lane)*8+j] = B[kb*32+(lane>>4)*8+j][nt*16+(lane&15)]
        int idx = (blockIdx.x - NB_GIN) * 256 + tid;
        if (idx >= 8 * 8 * 64) return;
        int lane = idx & 63;
        int kb = (idx >> 6) & 7;
        int nt = idx >> 9;
        int col = nt * 16 + (lane & 15);
        int kbase = kb * 32 + (lane >> 4) * 8;
        bf16_t v[8];
#pragma unroll
        for (int j = 0; j < 8; ++j) {
            int k = kbase + j;
            float w = (k < HID) ? Wl[k * HID + col] : Wr[(k - HID) * HID + col];
            v[j] = f2bf(w);
        }
        ushort4* o = (ushort4*)(Bp + (size_t)idx * 8);
        ushort4 lo, hi;
        lo.x = v[0]; lo.y = v[1]; lo.z = v[2]; lo.w = v[3];
        hi.x = v[4]; hi.y = v[5]; hi.z = v[6]; hi.w = v[7];
        o[0] = lo; o[1] = hi;
        return;
    }

    __shared__ float WgS[F_IN * HID];
    __shared__ float xsT[F_IN][XST];
    int node0 = blockIdx.x * GIN_NODES;
    {
        const float4* g = (const float4*)Wg;
        float4* s = (float4*)WgS;
        for (int i = tid; i < F_IN * HID / 4; i += 256) s[i] = g[i];
    }
    for (int i = tid; i < GIN_NODES * F_IN; i += 256) {
        int n = i / F_IN;
        int k = i - n * F_IN;
        int gn = node0 + n;
        if (gn >= NN) gn = NN - 1;
        xsT[k][n] = x[gn * F_IN + k];
    }
    __syncthreads();

    int fq = tid & 31, nq = tid >> 5;
    int f0 = fq * 4, nb = nq * 8;
    float acc[8][4];
#pragma unroll
    for (int i = 0; i < 8; ++i)
#pragma unroll
        for (int j = 0; j < 4; ++j) acc[i][j] = 0.f;

    for (int k = 0; k < F_IN; ++k) {
        float4 w = *(const float4*)&WgS[k * HID + f0];
        float4 xa = *(const float4*)&xsT[k][nb];
        float4 xb = *(const float4*)&xsT[k][nb + 4];
        float xv[8] = {xa.x, xa.y, xa.z, xa.w, xb.x, xb.y, xb.z, xb.w};
        float wv[4] = {w.x, w.y, w.z, w.w};
#pragma unroll
        for (int i = 0; i < 8; ++i)
#pragma unroll
            for (int j = 0; j < 4; ++j)
                acc[i][j] = fmaf(xv[i], wv[j], acc[i][j]);
    }

    float4 as4 = *(const float4*)(a_s + f0);
    float4 ad4 = *(const float4*)(a_d + f0);
    float ps[8], pd[8];
#pragma unroll
    for (int i = 0; i < 8; ++i) {
        int gn = node0 + nb + i;
        if (gn < NN) {
            ushort4 hv;
            hv.x = f2bf(acc[i][0]); hv.y = f2bf(acc[i][1]);
            hv.z = f2bf(acc[i][2]); hv.w = f2bf(acc[i][3]);
            *(ushort4*)(h + (size_t)gn * HID + f0) = hv;
        }
        ps[i] = acc[i][0] * as4.x + acc[i][1] * as4.y + acc[i][2] * as4.z + acc[i][3] * as4.w;
        pd[i] = acc[i][0] * ad4.x + acc[i][1] * ad4.y + acc[i][2] * ad4.z + acc[i][3] * ad4.w;
    }
#pragma unroll
    for (int off = 16; off > 0; off >>= 1) {
#pragma unroll
        for (int i = 0; i < 8; ++i) {
            ps[i] += __shfl_xor(ps[i], off);
            pd[i] += __shfl_xor(pd[i], off);
        }
    }
    if (fq == 0) {
#pragma unroll
        for (int i = 0; i < 8; ++i) {
            int gn = node0 + nb + i;
            if (gn < NN) { hs[gn] = ps[i]; hd[gn] = pd[i]; }
        }
    }
}

// ---------------- CSR: histogram ----------------
__global__ void k_hist(const int* __restrict__ dst, int* __restrict__ deg) {
    int e = blockIdx.x * blockDim.x + threadIdx.x;
    if (e < NE) atomicAdd(&deg[dst[e]], 1);
}

// ---------------- CSR: per-tile scan + last-block tile-prefix (no grid sync) ----------------
__global__ void k_scan(const int* __restrict__ deg, int* __restrict__ rptr,
                       int* __restrict__ bsum, int* __restrict__ bpre,
                       int* __restrict__ done) {
    int t = threadIdx.x;
    int tile = blockIdx.x;
    int i = tile * 256 + t;
    int v = (i < NN) ? deg[i] : 0;
    __shared__ int s[256];
    __shared__ int islast;
    s[t] = v;
    __syncthreads();
    for (int off = 1; off < 256; off <<= 1) {
        int xv = (t >= off) ? s[t - off] : 0;
        __syncthreads();
        s[t] += xv;
        __syncthreads();
    }
    if (i < NN) rptr[i] = s[t] - v;
    if (t == 255) bsum[tile] = s[255];
    __threadfence();
    if (t == 0) islast = (atomicAdd(done, 1) == NB_SCAN - 1);
    __syncthreads();
    if (!islast) return;
    int b = (t < NB_SCAN) ? atomicAdd(&bsum[t], 0) : 0;
    __syncthreads();
    s[t] = b;
    __syncthreads();
    for (int off = 1; off < 256; off <<= 1) {
        int xv = (t >= off) ? s[t - off] : 0;
        __syncthreads();
        s[t] += xv;
        __syncthreads();
    }
    if (t < NB_SCAN) bpre[t] = s[t] - b;
}

// ---------------- CSR: fill ----------------
__global__ void k_fill(const int* __restrict__ src, const int* __restrict__ dst,
                       const int* __restrict__ rptr, const int* __restrict__ bpre,
                       int* __restrict__ fillcnt, int* __restrict__ esrc) {
    int e = blockIdx.x * blockDim.x + threadIdx.x;
    if (e >= NE) return;
    int d = dst[e];
    int pos = rptr[d] + bpre[d >> 8] + atomicAdd(&fillcnt[d], 1);
    esrc[pos] = src[e];
}

// ---------------- GAT aggregation: wave-per-node, barrier-free ----------------
__global__ __launch_bounds__(256) void k_gat_agg(
    const int* __restrict__ rptr, const int* __restrict__ bpre,
    const int* __restrict__ deg, const int* __restrict__ esrc,
    const float* __restrict__ hs, const float* __restrict__ hd,
    const bf16_t* __restrict__ h, const float* __restrict__ bg,
    bf16_t* __restrict__ h1) {
    int tid = threadIdx.x;
    int row = blockIdx.x * 4 + (tid >> 6);
    if (row >= NN) return;
    int lane = tid & 63;
    int slot = lane >> 4;
    int f8 = lane & 15;

    int start = rptr[row] + bpre[row >> 8];
    int dn = deg[row];
    int end = start + dn;
    float hdr = hd[row];
    float wself = __expf(leaky(hs[row] + hdr));

    float a[8];
#pragma unroll
    for (int j = 0; j < 8; ++j) a[j] = 0.f;
    float denL = 0.f;

    if (slot == 0) {
        bf16x8 r = *(const bf16x8*)(h + (size_t)row * HID + f8 * 8);
#pragma unroll
        for (int j = 0; j < 8; ++j) a[j] = wself * bf2f((bf16_t)r[j]);
    }

    int e = start;
    for (; e + 8 <= end; e += 8) {
        int s0 = esrc[e + slot];
        int s1 = esrc[e + 4 + slot];
        float w0 = __expf(leaky(hs[s0] + hdr));
        float w1 = __expf(leaky(hs[s1] + hdr));
        bf16x8 r0 = *(const bf16x8*)(h + (size_t)s0 * HID + f8 * 8);
        bf16x8 r1 = *(const bf16x8*)(h + (size_t)s1 * HID + f8 * 8);
        denL += w0 + w1;
#pragma unroll
        for (int j = 0; j < 8; ++j) {
            a[j] = fmaf(w0, bf2f((bf16_t)r0[j]), a[j]);
            a[j] = fmaf(w1, bf2f((bf16_t)r1[j]), a[j]);
        }
    }
    for (; e < end; e += 4) {
        int i = e + slot;
        bool act = i < end;
        int sn = esrc[act ? i : end - 1];
        float w = act ? __expf(leaky(hs[sn] + hdr)) : 0.f;
        bf16x8 r = *(const bf16x8*)(h + (size_t)sn * HID + f8 * 8);
        denL += w;
#pragma unroll
        for (int j = 0; j < 8; ++j) a[j] = fmaf(w, bf2f((bf16_t)r[j]), a[j]);
    }

#pragma unroll
    for (int j = 0; j < 8; ++j) {
        a[j] += __shfl_xor(a[j], 16);
        a[j] += __shfl_xor(a[j], 32);
    }
    denL += __shfl_xor(denL, 16);
    denL += __shfl_xor(denL, 32);
    float inv = 1.f / (wself + denL);

    if (lane < 16) {
        float4 b0 = *(const float4*)(bg + lane * 8);
        float4 b1 = *(const float4*)(bg + lane * 8 + 4);
        float bb[8] = {b0.x, b0.y, b0.z, b0.w, b1.x, b1.y, b1.z, b1.w};
        bf16x8 o;
#pragma unroll
        for (int j = 0; j < 8; ++j) {
            float v = a[j] * inv + bb[j];
            o[j] = (short)f2bf(v > 0.f ? v : 0.f);
        }
        *(bf16x8*)(h1 + (size_t)row * HID + lane * 8) = o;
    }
}

// ---------------- Fused SAGE gather + MFMA dense ----------------
// 16 nodes/block, 4 waves. Gather: wave wv does nodes wv*4..+3 (1 node per wave-pass,
// same slot/f8 pattern as before) -> meanS/selfS in LDS. MFMA: wave wv does N-tiles
// {2wv, 2wv+1}; cross-wave Wout-dot reduction through prS.
__global__ __launch_bounds__(256) void k_sage_dense(
    const int* __restrict__ rptr, const int* __restrict__ bpre,
    const int* __restrict__ deg, const int* __restrict__ esrc,
    const bf16_t* __restrict__ h1, const bf16_t* __restrict__ Bp,
    const float* __restrict__ bl, const float* __restrict__ Wout,
    const float* __restrict__ bout, float* __restrict__ out) {
    __shared__ __align__(16) bf16_t meanS[SD_NODES][136];   // +8 pad: 272B rows, 16B aligned
    __shared__ __align__(16) bf16_t selfS[SD_NODES][136];
    __shared__ float prS[4][SD_NODES];
    int tid = threadIdx.x;
    int wv = tid >> 6;
    int lane = tid & 63;
    int slot = lane >> 4;
    int f8 = lane & 15;
    int node0 = blockIdx.x * SD_NODES;

    // ---- gather phase ----
#pragma unroll
    for (int i = 0; i < 4; ++i) {
        int ln = wv * 4 + i;
        int row = node0 + ln;
        int start = rptr[row] + bpre[row >> 8];
        int dn = deg[row];
        int end = start + dn;

        bf16x8 selfr;
        if (slot == 1) selfr = *(const bf16x8*)(h1 + (size_t)row * HID + f8 * 8);  // hoisted

        float a[8];
#pragma unroll
        for (int j = 0; j < 8; ++j) a[j] = 0.f;

        int e = start;
        for (; e + 8 <= end; e += 8) {
            int s0 = esrc[e + slot];
            int s1 = esrc[e + 4 + slot];
            bf16x8 r0 = *(const bf16x8*)(h1 + (size_t)s0 * HID + f8 * 8);
            bf16x8 r1 = *(const bf16x8*)(h1 + (size_t)s1 * HID + f8 * 8);
#pragma unroll
            for (int j = 0; j < 8; ++j)
                a[j] += bf2f((bf16_t)r0[j]) + bf2f((bf16_t)r1[j]);
        }
        for (; e < end; e += 4) {
            int ie = e + slot;
            bool act = ie < end;
            int sn = esrc[act ? ie : end - 1];
            bf16x8 r = *(const bf16x8*)(h1 + (size_t)sn * HID + f8 * 8);
            float w = act ? 1.f : 0.f;
#pragma unroll
            for (int j = 0; j < 8; ++j) a[j] = fmaf(w, bf2f((bf16_t)r[j]), a[j]);
        }

#pragma unroll
        for (int j = 0; j < 8; ++j) {
            a[j] += __shfl_xor(a[j], 16);
            a[j] += __shfl_xor(a[j], 32);
        }
        if (lane < 16) {
            float inv = 1.f / (float)(dn > 0 ? dn : 1);
            bf16x8 o;
#pragma unroll
            for (int j = 0; j < 8; ++j) o[j] = (short)f2bf(a[j] * inv);
            *(bf16x8*)&meanS[ln][lane * 8] = o;
        }
        if (slot == 1) *(bf16x8*)&selfS[ln][f8 * 8] = selfr;
    }
    __syncthreads();

    // ---- MFMA phase: wave wv -> N-tiles 2wv, 2wv+1 ----
    int arow = lane & 15;
    int kg = lane >> 4;
    const bf16x8* bp = (const bf16x8*)Bp;
    f32x4 acc0 = (f32x4){0.f, 0.f, 0.f, 0.f};
    f32x4 acc1 = (f32x4){0.f, 0.f, 0.f, 0.f};
    int n0 = wv * 2;

#pragma unroll
    for (int kb = 0; kb < 8; ++kb) {
        int k0 = kb * 32 + kg * 8;
        bf16x8 a = (kb < 4) ? *(const bf16x8*)&meanS[arow][k0]
                            : *(const bf16x8*)&selfS[arow][k0 - HID];
        bf16x8 b0 = bp[(((n0 + 0) * 8 + kb) << 6) + lane];
        bf16x8 b1 = bp[(((n0 + 1) * 8 + kb) << 6) + lane];
        acc0 = __builtin_amdgcn_mfma_f32_16x16x32_bf16(a, b0, acc0, 0, 0, 0);
        acc1 = __builtin_amdgcn_mfma_f32_16x16x32_bf16(a, b1, acc1, 0, 0, 0);
    }

    // epilogue: bias+relu+Wout partial dot over this wave's 32 feats
    float pr[4] = {0.f, 0.f, 0.f, 0.f};
    {
        int f0 = (n0 + 0) * 16 + arow;
        int f1 = (n0 + 1) * 16 + arow;
        float bl0 = bl[f0], bl1 = bl[f1];
        float wo0 = Wout[f0], wo1 = Wout[f1];
#pragma unroll
        for (int r = 0; r < 4; ++r) {
            float v0 = fmaxf(acc0[r] + bl0, 0.f);
            float v1 = fmaxf(acc1[r] + bl1, 0.f);
            pr[r] = fmaf(v0, wo0, fmaf(v1, wo1, pr[r]));
        }
    }
#pragma unroll
    for (int off = 8; off > 0; off >>= 1) {
#pragma unroll
        for (int r = 0; r < 4; ++r) pr[r] += __shfl_xor(pr[r], off);
    }
    if (arow == 0) {
#pragma unroll
        for (int r = 0; r < 4; ++r) prS[wv][kg * 4 + r] = pr[r];
    }
    __syncthreads();
    if (tid < SD_NODES) {
        float z = prS[0][tid] + prS[1][tid] + prS[2][tid] + prS[3][tid] + bout[0];
        out[node0 + tid] = 1.f / (1.f + __expf(-z));
    }
}

extern "C" void kernel_launch(void* const* d_in, const int* in_sizes, int n_in,
                              void* d_out, int out_size, void* d_ws, size_t ws_size,
                              hipStream_t stream) {
    const float* x    = (const float*)d_in[0];
    const int*   ei   = (const int*)d_in[1];
    const float* Wg   = (const float*)d_in[2];
    const float* a_s  = (const float*)d_in[3];
    const float* a_d  = (const float*)d_in[4];
    const float* bg   = (const float*)d_in[5];
    const float* Wl   = (const float*)d_in[6];
    const float* bl   = (const float*)d_in[7];
    const float* Wr   = (const float*)d_in[8];
    const float* Wout = (const float*)d_in[9];
    const float* bout = (const float*)d_in[10];
    float* out = (float*)d_out;

    const int* src = ei;
    const int* dst = ei + NE;

    bf16_t* h    = (bf16_t*)d_ws;                  // NN*HID bf16
    bf16_t* h1   = h + (size_t)NN * HID;           // NN*HID bf16
    bf16_t* Bp   = h1 + (size_t)NN * HID;          // 64 KB packed weights
    float* hs = (float*)(Bp + 8 * 8 * 64 * 8);     // NN
    float* hd = hs + NN;                           // NN
    int* deg     = (int*)(hd + NN);                // NN   -- zero region start
    int* fillcnt = deg + NN;                       // NN
    int* done    = fillcnt + NN;                   // 4    -- zero region end
    int* rptr    = done + 4;                       // NN
    int* bsum    = rptr + NN;                      // 256
    int* bpre    = bsum + 256;                     // 256
    int* esrc    = bpre + 256;                     // NE

    k_front<<<NB_GIN + NB_PACK + NB_ZERO, 256, 0, stream>>>(
        x, Wg, a_s, a_d, Wl, Wr, h, hs, hd, Bp, deg);

    k_hist<<<(NE + 255) / 256, 256, 0, stream>>>(dst, deg);
    k_scan<<<NB_SCAN, 256, 0, stream>>>(deg, rptr, bsum, bpre, done);
    k_fill<<<(NE + 255) / 256, 256, 0, stream>>>(src, dst, rptr, bpre, fillcnt, esrc);

    k_gat_agg<<<(NN + 3) / 4, 256, 0, stream>>>(rptr, bpre, deg, esrc, hs, hd, h, bg, h1);
    k_sage_dense<<<NB_SD, 256, 0, stream>>>(rptr, bpre, deg, esrc, h1, Bp, bl, Wout, bout, out);
}